// Round 3
// baseline (202.085 us; speedup 1.0000x reference)
//
#include <hip/hip_runtime.h>
#include <hip/hip_bf16.h>
#include <cstdint>
#include <cstddef>

// Problem constants
#define BS_TOT 12288   // 3 * 4096 rows
#define DIM    256     // embedding dim
#define BATCH_ 4096
#define NTILE  96      // BS_TOT / 128
#define NPAIR  4656    // NTILE*(NTILE+1)/2 — upper-triangular tile pairs

typedef _Float16 f16x8 __attribute__((ext_vector_type(8)));
typedef _Float16 f16x4 __attribute__((ext_vector_type(4)));
typedef float    f32x4 __attribute__((ext_vector_type(4)));

#define AS1 __attribute__((address_space(1)))
#define AS3 __attribute__((address_space(3)))

// ---------------------------------------------------------------------------
// Kernel 1: row-normalize (one wave per row) + zero den (saves a memset).
// ---------------------------------------------------------------------------
__global__ __launch_bounds__(256) void normalize_kernel(const float* __restrict__ x,
                                                        _Float16* __restrict__ xn,
                                                        float* __restrict__ invn,
                                                        float* __restrict__ den) {
  const int wave = threadIdx.x >> 6;
  const int lane = threadIdx.x & 63;
  const int row  = blockIdx.x * 4 + wave;
  const float4 v = ((const float4*)(x + (size_t)row * DIM))[lane];
  float ss = v.x*v.x + v.y*v.y + v.z*v.z + v.w*v.w;
  #pragma unroll
  for (int off = 1; off < 64; off <<= 1) ss += __shfl_xor(ss, off, 64);
  const float s = 1.0f / fmaxf(sqrtf(ss), 1e-6f);
  if (lane == 0) { invn[row] = s; den[row] = 0.0f; }
  f16x4 h;
  h.x = (_Float16)(v.x * s); h.y = (_Float16)(v.y * s);
  h.z = (_Float16)(v.z * s); h.w = (_Float16)(v.w * s);
  ((f16x4*)(xn + (size_t)row * DIM))[lane] = h;
}

// ---------------------------------------------------------------------------
// Kernel 2: symmetric tiled A@A^T, exp-fused, masked row/col sums into den.
//
// Single-barrier structure: the whole 128x256 A-tile (64 KB) is staged into
// LDS once (16 global_load_lds dwordx4 per thread), with an XOR swizzle
// baked into the SOURCE address so fragment ds_read_b128s are bank-uniform:
//   LDS slot (16B units) for data chunk (row, koff8) = row*32 + (koff8 ^ (row&31))
// B is streamed straight from global into registers (16 f16x8 fragments,
// prefetched BEFORE the barrier so their latency hides under the A drain).
// Wave w computes the 128-row x 32-col strip [w*32, w*32+32).
// Mask: exclude iff col%4 == row%4 -> (c16&3) == r (tile-invariant, since all
// tile/strip bases are multiples of 4). Diagonal entries of the full matrix
// satisfy col%4==row%4, so self-similarity is masked automatically.
// ---------------------------------------------------------------------------
__global__ __launch_bounds__(256) void gemm_den_kernel(const _Float16* __restrict__ xn,
                                                       float* __restrict__ den) {
  __shared__ _Float16 As[128 * 256];   // 64 KB, swizzled

  const int tid = threadIdx.x;

  // triangular decode: blockIdx.x -> (tI <= tJ)
  const int t = blockIdx.x;
  int j = (int)((sqrtf(8.0f * (float)t + 1.0f) - 1.0f) * 0.5f);
  while ((j + 1) * (j + 2) / 2 <= t) j++;
  while (j * (j + 1) / 2 > t) j--;
  const int tI = t - j * (j + 1) / 2;   // 0..j
  const int tJ = j;

  const int wave = tid >> 6, lane = tid & 63;
  const int quad = lane >> 4, c16 = lane & 15;

  const _Float16* Ab = xn + (size_t)tI * 128 * DIM;
  const _Float16* Bb = xn + (size_t)tJ * 128 * DIM;

  // ---- B prefetch: 16 fragments (kstep 0..7 x ni 0..1) straight to VGPRs.
  // frag (ni,kstep): lane reads B row (wave*32 + ni*16 + c16),
  // k = kstep*32 + quad*8, 16 bytes.
  f16x8 bf[8][2];
  #pragma unroll
  for (int ks = 0; ks < 8; ks++)
    #pragma unroll
    for (int ni = 0; ni < 2; ni++)
      bf[ks][ni] = *(const f16x8*)(Bb + (size_t)(wave*32 + ni*16 + c16) * DIM
                                      + ks*32 + quad*8);

  // ---- A staging: 16 instrs x 256 threads x 16B = 64 KB, swizzled source.
  #pragma unroll
  for (int i = 0; i < 16; i++) {
    const int s    = i * 256 + tid;          // LDS slot (16B units)
    const int row  = s >> 5;                 // 0..127
    const int k8   = (s & 31) ^ (row & 31);  // source koff8 (8-f16 units)
    __builtin_amdgcn_global_load_lds((AS1 void*)(Ab + (size_t)row * DIM + k8 * 8),
                                     (AS3 void*)(As + s * 8), 16, 0, 0);
  }
  __syncthreads();   // the ONLY barrier: drains A staging (and B prefetch)

  // ---- K-loop: 8 steps of 32; per step 8 A-frag ds_reads + 16 MFMA.
  f32x4 acc[8][2] = {};
  #pragma unroll
  for (int ks = 0; ks < 8; ks++) {
    f16x8 af[8];
    #pragma unroll
    for (int mi = 0; mi < 8; mi++) {
      const int row = mi * 16 + c16;
      const int k8  = (ks * 4 + quad) ^ (row & 31);
      af[mi] = *(const f16x8*)(As + (row * 32 + k8) * 8);
    }
    #pragma unroll
    for (int mi = 0; mi < 8; mi++)
      #pragma unroll
      for (int ni = 0; ni < 2; ni++)
        acc[mi][ni] = __builtin_amdgcn_mfma_f32_16x16x32_f16(af[mi], bf[ks][ni], acc[mi][ni], 0, 0, 0);
  }

  // ---- Epilogue. C/D layout: col = c16 (within frag), row = quad*4 + r.
  const int rowBase = tI * 128;
  const int colBase = tJ * 128 + wave * 32;
  float colsum[2] = {0.f, 0.f};

  #pragma unroll
  for (int mi = 0; mi < 8; mi++) {
    #pragma unroll
    for (int r = 0; r < 4; r++) {
      float rs = 0.0f;
      if ((c16 & 3) != r) {            // include iff col%4 != row%4
        #pragma unroll
        for (int ni = 0; ni < 2; ni++) {
          const float e = __expf(acc[mi][ni][r] * 10.0f);
          rs += e;
          colsum[ni] += e;
        }
      }
      // reduce over the 16 col-lanes (c16) of this quad
      rs += __shfl_xor(rs, 1, 64);
      rs += __shfl_xor(rs, 2, 64);
      rs += __shfl_xor(rs, 4, 64);
      rs += __shfl_xor(rs, 8, 64);
      if (c16 == 0) atomicAdd(&den[rowBase + mi*16 + quad*4 + r], rs);
    }
  }

  if (tI != tJ) {                      // off-diagonal: scatter column sums too
    #pragma unroll
    for (int ni = 0; ni < 2; ni++) {
      float cs = colsum[ni];
      cs += __shfl_xor(cs, 16, 64);
      cs += __shfl_xor(cs, 32, 64);
      if (quad == 0) atomicAdd(&den[colBase + ni*16 + c16], cs);
    }
  }
}

// ---------------------------------------------------------------------------
// Kernel 3: numerators (fp32, exact path) + final loss.
// ---------------------------------------------------------------------------
__global__ __launch_bounds__(256) void loss_kernel(const float* __restrict__ x,
                                                   const float* __restrict__ invn,
                                                   const float* __restrict__ den,
                                                   float* __restrict__ out) {
  __shared__ float part[4];
  const int wave = threadIdx.x >> 6, lane = threadIdx.x & 63;
  const int p = blockIdx.x * 4 + wave;
  const float4 a = ((const float4*)(x + (size_t)p * DIM))[lane];
  const float4 b = ((const float4*)(x + (size_t)(BATCH_ + p) * DIM))[lane];
  const float4 c = ((const float4*)(x + (size_t)(2*BATCH_ + p) * DIM))[lane];
  float d12 = a.x*b.x + a.y*b.y + a.z*b.z + a.w*b.w;
  float d13 = a.x*c.x + a.y*c.y + a.z*c.z + a.w*c.w;
  float d23 = b.x*c.x + b.y*c.y + b.z*c.z + b.w*c.w;
  #pragma unroll
  for (int off = 1; off < 64; off <<= 1) {
    d12 += __shfl_xor(d12, off, 64);
    d13 += __shfl_xor(d13, off, 64);
    d23 += __shfl_xor(d23, off, 64);
  }
  if (lane == 0) {
    const float s1 = invn[p], s2 = invn[BATCH_ + p], s3 = invn[2*BATCH_ + p];
    const float z12 = d12 * s1 * s2 * 10.0f;
    const float z13 = d13 * s1 * s3 * 10.0f;
    const float z23 = d23 * s2 * s3 * 10.0f;
    const float n12 = __expf(z12), n13 = __expf(z13), n23 = __expf(z23);
    const float e1 = den[p], e2 = den[BATCH_ + p], e3 = den[2*BATCH_ + p];
    part[wave] = logf(n12 + e1) + logf(n12 + e2) - 2.0f * z12
               + logf(n13 + e1) + logf(n13 + e3) - 2.0f * z13
               + logf(n23 + e2) + logf(n23 + e3) - 2.0f * z23;
  }
  __syncthreads();
  if (threadIdx.x == 0) {
    atomicAdd(out, (part[0] + part[1] + part[2] + part[3]) * (1.0f / (2.0f * BATCH_)));
  }
}

// ---------------------------------------------------------------------------
extern "C" void kernel_launch(void* const* d_in, const int* in_sizes, int n_in,
                              void* d_out, int out_size, void* d_ws, size_t ws_size,
                              hipStream_t stream) {
  const float* x = (const float*)d_in[0];
  float* out = (float*)d_out;

  char* ws = (char*)d_ws;
  _Float16* xn   = (_Float16*)ws;                                        // 6 MB
  float*    invn = (float*)(ws + (size_t)BS_TOT * DIM * 2);              // 48 KB
  float*    den  = (float*)(ws + (size_t)BS_TOT * DIM * 2 + BS_TOT * 4); // 48 KB

  hipMemsetAsync(d_out, 0, out_size * sizeof(float), stream);

  normalize_kernel<<<BS_TOT / 4, 256, 0, stream>>>(x, xn, invn, den);
  gemm_den_kernel<<<NPAIR, 256, 0, stream>>>(xn, den);
  loss_kernel<<<BATCH_ / 4, 256, 0, stream>>>(x, invn, den, out);
}

// Round 4
// 180.174 us; speedup vs baseline: 1.1216x; 1.1216x over previous
//
#include <hip/hip_runtime.h>
#include <hip/hip_bf16.h>
#include <cstdint>
#include <cstddef>

// Problem constants
#define BS_TOT 12288   // 3 * 4096 rows
#define DIM    256     // embedding dim
#define BATCH_ 4096
#define NG     48      // column groups of 256
#define NBLK   2352    // NG*NG + NG = triangular (g, i<=2g+1) pairs

typedef float f32x16 __attribute__((ext_vector_type(16)));

// ---------------------------------------------------------------------------
// Kernel 1: row-normalize -> fp8 e4m3 rows (for MFMA) + fp32 inv-norms
// (exact numerator path) + zero den.
// ---------------------------------------------------------------------------
__global__ __launch_bounds__(256) void normalize_kernel(const float* __restrict__ x,
                                                        uint8_t* __restrict__ xn,
                                                        float* __restrict__ invn,
                                                        float* __restrict__ den) {
  const int wave = threadIdx.x >> 6;
  const int lane = threadIdx.x & 63;
  const int row  = blockIdx.x * 4 + wave;
  const float4 v = ((const float4*)(x + (size_t)row * DIM))[lane];
  float ss = v.x*v.x + v.y*v.y + v.z*v.z + v.w*v.w;
  #pragma unroll
  for (int off = 1; off < 64; off <<= 1) ss += __shfl_xor(ss, off, 64);
  const float s = 1.0f / fmaxf(sqrtf(ss), 1e-6f);
  if (lane == 0) { invn[row] = s; den[row] = 0.0f; }
  unsigned int w = __builtin_amdgcn_cvt_pk_fp8_f32(v.x * s, v.y * s, 0u, false);
  w = __builtin_amdgcn_cvt_pk_fp8_f32(v.z * s, v.w * s, w, true);
  ((unsigned int*)(xn + (size_t)row * DIM))[lane] = w;
}

// ---------------------------------------------------------------------------
// Kernel 2: symmetric A@A^T (fp8 e4m3, 32x32x16 MFMA), exp-fused, masked
// row/col sums into den.
//
// Block = 128 rows (tile i) x 256 cols (group g), 4 waves x (128x64), one
// K-pass, ONE barrier. A panel (128x256 B = 32 KB) staged via XOR-swizzled
// ds_write_b64: slot8(row,k8) = row*32 + (k8 ^ (row&31))  -> all LDS reads/
// writes are <=2-way bank aliased (free). B strips live in registers
// (bf[16][2] = 64 VGPRs/lane, loaded straight from global/L2).
//
// LDS-traffic model (the R1-R3 bottleneck): A-reads = 4 waves x 32 KB =
// 128 KB per 128x256 output vs MFMA 8192 cyc/SIMD -> MFMA-dominant.
//
// Triangular coverage: block (g, i<=2g+1); wave w owns col tile jt = 2g+(w>>1);
//   jt < i  : skip (pair handled by its transpose owner)
//   jt == i : masked row sums only (diagonal tile, counted once)
//   jt > i  : masked row sums to den[rows(i)] AND col sums to den[cols(jt)]
// Mask: exclude iff col%4 == row%4. Bases are multiples of 4, so per-lane:
// include iff ((lane&31) ^ reg) & 3 != 0  (32x32 C/D: col=lane&31,
// row=(reg&3)+8*(reg>>2)+4*(lane>>5) — HW-verified, dtype-independent).
// ---------------------------------------------------------------------------
__global__ __launch_bounds__(256, 2) void gemm_den_kernel(const uint8_t* __restrict__ xn,
                                                          float* __restrict__ den) {
  __shared__ unsigned long long As[128 * 32];   // 32 KB, 8-B slots, swizzled

  const int tid = threadIdx.x;

  // decode blockIdx.x -> (g, i): cum(g) = g*(g+1), i in [0, 2g+2)
  const int t = blockIdx.x;
  int g = (int)((sqrtf(4.0f * (float)t + 1.0f) - 1.0f) * 0.5f);
  while ((g + 1) * (g + 2) <= t) g++;
  while (g * (g + 1) > t) g--;
  const int i = t - g * (g + 1);

  const int wave = tid >> 6, lane = tid & 63;
  const int l31 = lane & 31, half = lane >> 5;

  const uint8_t* Ab  = xn + (size_t)i * 128 * DIM;
  const int      colW = g * 256 + wave * 64;      // wave's first global col
  const uint8_t* BbW  = xn + (size_t)colW * DIM;
  const int      jt   = colW >> 7;                // wave's col tile

  // ---- A staging (issue first: it gates the barrier). 16-B chunks -> two
  // swizzled 8-B LDS slots each. 8 chunks per thread.
  ulonglong2 chunk[8];
  #pragma unroll
  for (int c = 0; c < 8; c++) {
    const int q = c * 256 + tid;
    chunk[c] = *(const ulonglong2*)(Ab + (size_t)(q >> 4) * DIM + (q & 15) * 16);
  }
  #pragma unroll
  for (int c = 0; c < 8; c++) {
    const int q = c * 256 + tid;
    const int row = q >> 4, k16 = q & 15;
    As[row * 32 + ((2 * k16)     ^ (row & 31))] = chunk[c].x;
    As[row * 32 + ((2 * k16 + 1) ^ (row & 31))] = chunk[c].y;
  }

  // ---- B prefetch: bf[ks][ni], row = colW + ni*32 + l31, k = ks*16 + half*8.
  long bf[16][2];
  #pragma unroll
  for (int ks = 0; ks < 16; ks++)
    #pragma unroll
    for (int ni = 0; ni < 2; ni++)
      bf[ks][ni] = *(const long*)(BbW + (size_t)(ni * 32 + l31) * DIM + ks * 16 + half * 8);

  __syncthreads();   // the ONLY barrier

  if (jt < i) return;                 // transpose owner handles this pair
  const bool doCol = (jt > i);

  // ---- K-loop: 16 steps of 16; per step 4 swizzled ds_read_b64 + 8 MFMA.
  f32x16 acc[4][2] = {};
  #pragma unroll
  for (int ks = 0; ks < 16; ks++) {
    long af[4];
    #pragma unroll
    for (int mi = 0; mi < 4; mi++) {
      const int row = mi * 32 + l31;
      const int k8  = (2 * ks + half) ^ (row & 31);
      af[mi] = (long)As[row * 32 + k8];
    }
    #pragma unroll
    for (int mi = 0; mi < 4; mi++)
      #pragma unroll
      for (int ni = 0; ni < 2; ni++)
        acc[mi][ni] = __builtin_amdgcn_mfma_f32_32x32x16_fp8_fp8(af[mi], bf[ks][ni], acc[mi][ni], 0, 0, 0);
  }

  // ---- Epilogue: E = exp(10*S); masked row sums + (off-diag) col sums.
  float colsum[2] = {0.f, 0.f};
  #pragma unroll
  for (int mi = 0; mi < 4; mi++) {
    #pragma unroll
    for (int r = 0; r < 16; r++) {
      float rs = 0.0f;
      if (((l31 ^ r) & 3) != 0) {     // include iff col%4 != row%4
        #pragma unroll
        for (int ni = 0; ni < 2; ni++) {
          const float e = __expf(acc[mi][ni][r] * 10.0f);
          rs += e;
          colsum[ni] += e;
        }
      }
      rs += __shfl_xor(rs, 1, 64);
      rs += __shfl_xor(rs, 2, 64);
      rs += __shfl_xor(rs, 4, 64);
      rs += __shfl_xor(rs, 8, 64);
      rs += __shfl_xor(rs, 16, 64);
      if (l31 == 0) {
        const int lr = mi * 32 + (r & 3) + 8 * (r >> 2) + 4 * half;
        atomicAdd(&den[i * 128 + lr], rs);
      }
    }
  }
  if (doCol) {
    #pragma unroll
    for (int ni = 0; ni < 2; ni++) {
      const float cs = colsum[ni] + __shfl_xor(colsum[ni], 32, 64);
      if (half == 0) atomicAdd(&den[colW + ni * 32 + l31], cs);
    }
  }
}

// ---------------------------------------------------------------------------
// Kernel 3: numerators (fp32, exact path) + final loss.
// ---------------------------------------------------------------------------
__global__ __launch_bounds__(256) void loss_kernel(const float* __restrict__ x,
                                                   const float* __restrict__ invn,
                                                   const float* __restrict__ den,
                                                   float* __restrict__ out) {
  __shared__ float part[4];
  const int wave = threadIdx.x >> 6, lane = threadIdx.x & 63;
  const int p = blockIdx.x * 4 + wave;
  const float4 a = ((const float4*)(x + (size_t)p * DIM))[lane];
  const float4 b = ((const float4*)(x + (size_t)(BATCH_ + p) * DIM))[lane];
  const float4 c = ((const float4*)(x + (size_t)(2*BATCH_ + p) * DIM))[lane];
  float d12 = a.x*b.x + a.y*b.y + a.z*b.z + a.w*b.w;
  float d13 = a.x*c.x + a.y*c.y + a.z*c.z + a.w*c.w;
  float d23 = b.x*c.x + b.y*c.y + b.z*c.z + b.w*c.w;
  #pragma unroll
  for (int off = 1; off < 64; off <<= 1) {
    d12 += __shfl_xor(d12, off, 64);
    d13 += __shfl_xor(d13, off, 64);
    d23 += __shfl_xor(d23, off, 64);
  }
  if (lane == 0) {
    const float s1 = invn[p], s2 = invn[BATCH_ + p], s3 = invn[2*BATCH_ + p];
    const float z12 = d12 * s1 * s2 * 10.0f;
    const float z13 = d13 * s1 * s3 * 10.0f;
    const float z23 = d23 * s2 * s3 * 10.0f;
    const float n12 = __expf(z12), n13 = __expf(z13), n23 = __expf(z23);
    const float e1 = den[p], e2 = den[BATCH_ + p], e3 = den[2*BATCH_ + p];
    part[wave] = logf(n12 + e1) + logf(n12 + e2) - 2.0f * z12
               + logf(n13 + e1) + logf(n13 + e3) - 2.0f * z13
               + logf(n23 + e2) + logf(n23 + e3) - 2.0f * z23;
  }
  __syncthreads();
  if (threadIdx.x == 0) {
    atomicAdd(out, (part[0] + part[1] + part[2] + part[3]) * (1.0f / (2.0f * BATCH_)));
  }
}

// ---------------------------------------------------------------------------
extern "C" void kernel_launch(void* const* d_in, const int* in_sizes, int n_in,
                              void* d_out, int out_size, void* d_ws, size_t ws_size,
                              hipStream_t stream) {
  const float* x = (const float*)d_in[0];
  float* out = (float*)d_out;

  char* ws = (char*)d_ws;
  uint8_t* xn   = (uint8_t*)ws;                                      // 3 MB fp8
  float*   invn = (float*)(ws + (size_t)BS_TOT * DIM);               // 48 KB
  float*   den  = (float*)(ws + (size_t)BS_TOT * DIM + BS_TOT * 4);  // 48 KB

  hipMemsetAsync(d_out, 0, out_size * sizeof(float), stream);

  normalize_kernel<<<BS_TOT / 4, 256, 0, stream>>>(x, xn, invn, den);
  gemm_den_kernel<<<NBLK, 256, 0, stream>>>(xn, den);
  loss_kernel<<<BATCH_ / 4, 256, 0, stream>>>(x, invn, den, out);
}

// Round 5
// 140.701 us; speedup vs baseline: 1.4363x; 1.2805x over previous
//
#include <hip/hip_runtime.h>
#include <hip/hip_bf16.h>
#include <cstdint>
#include <cstddef>

// Problem constants
#define BS_TOT 12288   // 3 * 4096 rows
#define DIM    256     // embedding dim
#define BATCH_ 4096
#define NTILE  96      // BS_TOT / 128

typedef float f32x16 __attribute__((ext_vector_type(16)));

// ---------------------------------------------------------------------------
// Kernel 1: row-normalize -> fp8 e4m3 rows (for MFMA) + fp32 inv-norms
// (exact numerator path) + zero den + zero out (folds the memset dispatch).
// ---------------------------------------------------------------------------
__global__ __launch_bounds__(256) void normalize_kernel(const float* __restrict__ x,
                                                        uint8_t* __restrict__ xn,
                                                        float* __restrict__ invn,
                                                        float* __restrict__ den,
                                                        float* __restrict__ out,
                                                        int osz) {
  if (blockIdx.x == 0 && (int)threadIdx.x < osz) out[threadIdx.x] = 0.0f;
  const int wave = threadIdx.x >> 6;
  const int lane = threadIdx.x & 63;
  const int row  = blockIdx.x * 4 + wave;
  const float4 v = ((const float4*)(x + (size_t)row * DIM))[lane];
  float ss = v.x*v.x + v.y*v.y + v.z*v.z + v.w*v.w;
  #pragma unroll
  for (int off = 1; off < 64; off <<= 1) ss += __shfl_xor(ss, off, 64);
  const float s = 1.0f / fmaxf(sqrtf(ss), 1e-6f);
  if (lane == 0) { invn[row] = s; den[row] = 0.0f; }
  unsigned int w = __builtin_amdgcn_cvt_pk_fp8_f32(v.x * s, v.y * s, 0u, false);
  w = __builtin_amdgcn_cvt_pk_fp8_f32(v.z * s, v.w * s, w, true);
  ((unsigned int*)(xn + (size_t)row * DIM))[lane] = w;
}

// ---------------------------------------------------------------------------
// Kernel 2: full ordered tile grid (96x96) of A@A^T (fp8 e4m3, 32x32x16
// MFMA), exp-fused, masked COLUMN sums into den.
//
// Why column sums: in the 32x32 C/D layout (col=lane&31,
// row=(reg&3)+8*(reg>>2)+4*(lane>>5) — HW-verified), summing over ROWS is
// in-register (free) while summing over COLS is cross-lane (the 320
// shuffle-ops/wave that dominated R1-R2). E and the mod-4 mask are
// symmetric, so accumulating masked column sums over ALL ordered tiles
// gives exactly den. Cost: 2x MFMA of the symmetric scheme; epilogue is
// ~64 exps/lane + 1 shuffle + 1 atomic per (wave,ni).
//
// Both operands staged in LDS (32 KB each) via coalesced dwordx4 loads +
// XOR-swizzled ds_write_b64 (R4-proven: frag ds_read_b64 is <=2-way bank
// aliased = free):   slot8(row,k8) = row*32 + (k8 ^ (row&31))
// Block = 4 waves in 2x2, each wave 64x64 via 2x2 of 32x32x16. One barrier.
// Mask: exclude iff col%4 == row%4 -> ((l31^r)&3)==0 per acc element (all
// tile bases are multiples of 4).
// ---------------------------------------------------------------------------
__global__ __launch_bounds__(256, 2) void gemm_den_kernel(const uint8_t* __restrict__ xn,
                                                          float* __restrict__ den) {
  __shared__ unsigned long long As[128 * 32];   // 32 KB, swizzled 8-B slots
  __shared__ unsigned long long Bs[128 * 32];   // 32 KB

  const int tid = threadIdx.x;
  const int tJ  = blockIdx.x;    // column tile (fast-varying: B panels cycle through L2)
  const int tI  = blockIdx.y;    // row tile

  const int wave = tid >> 6, lane = tid & 63;
  const int wr   = wave >> 1, wc = wave & 1;
  const int l31  = lane & 31, half = lane >> 5;

  const uint8_t* Ab = xn + (size_t)tI * 128 * DIM;
  const uint8_t* Bb = xn + (size_t)tJ * 128 * DIM;

  // ---- Stage A and B: per thread 8 chunks of 16 B each (coalesced), then
  // two swizzled 8-B LDS writes per chunk.
  ulonglong2 chA[8], chB[8];
  #pragma unroll
  for (int c = 0; c < 8; c++) {
    const int q = c * 256 + tid;
    const size_t off = (size_t)(q >> 4) * DIM + (size_t)(q & 15) * 16;
    chA[c] = *(const ulonglong2*)(Ab + off);
    chB[c] = *(const ulonglong2*)(Bb + off);
  }
  #pragma unroll
  for (int c = 0; c < 8; c++) {
    const int q = c * 256 + tid;
    const int row = q >> 4, k16 = q & 15;
    const int s0 = row * 32 + ((2 * k16)     ^ (row & 31));
    const int s1 = row * 32 + ((2 * k16 + 1) ^ (row & 31));
    As[s0] = chA[c].x; As[s1] = chA[c].y;
    Bs[s0] = chB[c].x; Bs[s1] = chB[c].y;
  }
  __syncthreads();   // the ONLY barrier

  // ---- K-loop: 16 steps of K=16; per step 2 A-frag + 2 B-frag swizzled
  // ds_read_b64 + 4 MFMA. Frag layout (R4-verified): lane holds 8 bytes of
  // row (l31), k-offset (ks*16 + half*8)  -> k8 index = 2*ks + half.
  f32x16 acc[2][2] = {};
  #pragma unroll
  for (int ks = 0; ks < 16; ks++) {
    long af[2], bf[2];
    #pragma unroll
    for (int mi = 0; mi < 2; mi++) {
      const int row = wr * 64 + mi * 32 + l31;
      af[mi] = (long)As[row * 32 + ((2 * ks + half) ^ (row & 31))];
    }
    #pragma unroll
    for (int ni = 0; ni < 2; ni++) {
      const int row = wc * 64 + ni * 32 + l31;
      bf[ni] = (long)Bs[row * 32 + ((2 * ks + half) ^ (row & 31))];
    }
    #pragma unroll
    for (int mi = 0; mi < 2; mi++)
      #pragma unroll
      for (int ni = 0; ni < 2; ni++)
        acc[mi][ni] = __builtin_amdgcn_mfma_f32_32x32x16_fp8_fp8(af[mi], bf[ni], acc[mi][ni], 0, 0, 0);
  }

  // ---- Epilogue: den[col] += sum over this wave's 64 rows of masked
  // exp(10*S). Row index mod 4 == r&3 (all other row terms are =0 mod 4),
  // col mod 4 == l31&3 -> include iff ((l31^r)&3)!=0. In-register sum over
  // (mi, r), one shfl to combine the two half-groups (disjoint rows, same
  // col), 32-lane atomic per ni.
  const int colBase = tJ * 128 + wc * 64;
  #pragma unroll
  for (int ni = 0; ni < 2; ni++) {
    float cs = 0.0f;
    #pragma unroll
    for (int mi = 0; mi < 2; mi++)
      #pragma unroll
      for (int r = 0; r < 16; r++)
        if (((l31 ^ r) & 3) != 0)
          cs += __expf(acc[mi][ni][r] * 10.0f);
    cs += __shfl_xor(cs, 32, 64);
    if (half == 0) atomicAdd(&den[colBase + ni * 32 + l31], cs);
  }
}

// ---------------------------------------------------------------------------
// Kernel 3: numerators (fp32, exact path) + final loss.
// ---------------------------------------------------------------------------
__global__ __launch_bounds__(256) void loss_kernel(const float* __restrict__ x,
                                                   const float* __restrict__ invn,
                                                   const float* __restrict__ den,
                                                   float* __restrict__ out) {
  __shared__ float part[4];
  const int wave = threadIdx.x >> 6, lane = threadIdx.x & 63;
  const int p = blockIdx.x * 4 + wave;
  const float4 a = ((const float4*)(x + (size_t)p * DIM))[lane];
  const float4 b = ((const float4*)(x + (size_t)(BATCH_ + p) * DIM))[lane];
  const float4 c = ((const float4*)(x + (size_t)(2*BATCH_ + p) * DIM))[lane];
  float d12 = a.x*b.x + a.y*b.y + a.z*b.z + a.w*b.w;
  float d13 = a.x*c.x + a.y*c.y + a.z*c.z + a.w*c.w;
  float d23 = b.x*c.x + b.y*c.y + b.z*c.z + b.w*c.w;
  #pragma unroll
  for (int off = 1; off < 64; off <<= 1) {
    d12 += __shfl_xor(d12, off, 64);
    d13 += __shfl_xor(d13, off, 64);
    d23 += __shfl_xor(d23, off, 64);
  }
  if (lane == 0) {
    const float s1 = invn[p], s2 = invn[BATCH_ + p], s3 = invn[2*BATCH_ + p];
    const float z12 = d12 * s1 * s2 * 10.0f;
    const float z13 = d13 * s1 * s3 * 10.0f;
    const float z23 = d23 * s2 * s3 * 10.0f;
    const float n12 = __expf(z12), n13 = __expf(z13), n23 = __expf(z23);
    const float e1 = den[p], e2 = den[BATCH_ + p], e3 = den[2*BATCH_ + p];
    part[wave] = logf(n12 + e1) + logf(n12 + e2) - 2.0f * z12
               + logf(n13 + e1) + logf(n13 + e3) - 2.0f * z13
               + logf(n23 + e2) + logf(n23 + e3) - 2.0f * z23;
  }
  __syncthreads();
  if (threadIdx.x == 0) {
    atomicAdd(out, (part[0] + part[1] + part[2] + part[3]) * (1.0f / (2.0f * BATCH_)));
  }
}

// ---------------------------------------------------------------------------
extern "C" void kernel_launch(void* const* d_in, const int* in_sizes, int n_in,
                              void* d_out, int out_size, void* d_ws, size_t ws_size,
                              hipStream_t stream) {
  const float* x = (const float*)d_in[0];
  float* out = (float*)d_out;

  char* ws = (char*)d_ws;
  uint8_t* xn   = (uint8_t*)ws;                                      // 3 MB fp8
  float*   invn = (float*)(ws + (size_t)BS_TOT * DIM);               // 48 KB
  float*   den  = (float*)(ws + (size_t)BS_TOT * DIM + BS_TOT * 4);  // 48 KB

  normalize_kernel<<<BS_TOT / 4, 256, 0, stream>>>(x, xn, invn, den, out, out_size);
  gemm_den_kernel<<<dim3(NTILE, NTILE), 256, 0, stream>>>(xn, den);
  loss_kernel<<<BATCH_ / 4, 256, 0, stream>>>(x, invn, den, out);
}